// Round 3
// baseline (74.343 us; speedup 1.0000x reference)
//
#include <hip/hip_runtime.h>

#define SP 56
#define CH 64
#define XSTRIDE 3136   // 56*56 = per-j stride in x, per-i stride in out

// ---------------------------------------------------------------------------
// Prep: build combined coefficient tables from W (64,3,2,64) = W[i][kt][l][j].
// For o>=1 the reference collapses to a 4-tap vertical correlation:
//   b=o-2: C0=W[i,0,1,j]; b=o-1: C1=W[i,0,0,j]+W[i,1,1,j];
//   b=o  : C2=W[i,1,0,j]+W[i,2,1,j]; b=o+1: C3=W[i,2,0,j]
// o==0 wraps (o-1 -> 55): taps rows {0,1,54,55} with
//   D = {W[i,1,0,j], W[i,2,0,j], W[i,0,1,j], W[i,1,1,j]}
// Layout: Cv[j*64+i] = float4(C0..C3); D table at float4 offset 4096.
// ---------------------------------------------------------------------------
__global__ void tsc_prep(const float* __restrict__ W, float4* __restrict__ Cv) {
  int t = blockIdx.x * blockDim.x + threadIdx.x;
  if (t >= CH * CH) return;
  int i = t & 63;
  int j = t >> 6;
  const float* Wi = W + i * 384 + j;   // W[i][kt][l][j]: kt stride 128, l stride 64
  float w00 = Wi[0];
  float w01 = Wi[64];
  float w10 = Wi[128];
  float w11 = Wi[192];
  float w20 = Wi[256];
  float w21 = Wi[320];
  Cv[j * 64 + i]        = make_float4(w01, w00 + w11, w10 + w21, w20);
  Cv[4096 + j * 64 + i] = make_float4(w10, w20, w01, w11);
}

// ---------------------------------------------------------------------------
// Main: block = (og 0..13, nc 0..27) -> 2 output columns n = 2nc, 2nc+1.
// 256 threads = 4 waves; wave w owns j in [16w,16w+16), lane = out channel i.
// Cv fragments are PREFETCHED into registers before the staging barrier so
// their L2 latency overlaps the x staging. Top edge (g>=56) handled by
// zero-pad at staging; only og==0 takes the wrap/D-tap branch.
// ---------------------------------------------------------------------------
__global__ __launch_bounds__(256) void tsc_main(const float* __restrict__ x,
                                                const float4* __restrict__ Cv,
                                                float* __restrict__ out) {
  __shared__ float xs[2][CH][8];       // 4 KB: xs[col][j][b], row g = o0-2+b
  __shared__ float red[4][2][4][64];   // 8 KB: red[wave][col][s][i]

  const int t  = threadIdx.x;
  const int i  = t & 63;               // output channel (lane)
  const int w  = t >> 6;               // wave id 0..3
  const int og = blockIdx.x;           // 0..13
  const int nc = blockIdx.y;           // 0..27
  const int o0 = og * 4;
  const int n0 = nc * 2;
  const int ns0 = (n0 + SP - 1) % SP;  // (n0-1) mod 56
  const int ns1 = n0;                  // (n0+1-1) mod 56

  // ---- issue staging loads (4 per thread) ----
  float xv[4];
#pragma unroll
  for (int k = 0; k < 4; ++k) {
    int u = t + k * 256;               // 0..1023
    int col = u >> 9;
    int j = (u >> 3) & 63;
    int b = u & 7;
    int g = o0 - 2 + b;
    if (g < 0) g += SP;                // circular bottom (only og==0)
    int ns = col ? ns1 : ns0;
    xv[k] = (g < SP) ? x[j * XSTRIDE + ns * SP + g] : 0.f;  // zero-pad top
  }

  // ---- prefetch coefficient fragments (overlaps staging latency) ----
  const float4* cb = Cv + i;
  const int j0 = w * 16;
  float4 creg[16];
#pragma unroll
  for (int jj = 0; jj < 16; ++jj) creg[jj] = cb[(j0 + jj) * 64];

  // ---- commit staged values to LDS ----
#pragma unroll
  for (int k = 0; k < 4; ++k) {
    int u = t + k * 256;
    int col = u >> 9;
    int j = (u >> 3) & 63;
    int b = u & 7;
    xs[col][j][b] = xv[k];
  }
  __syncthreads();

  // ---- per-wave partial sums over 16 j values, 2 columns ----
  float a00 = 0.f, a01 = 0.f, a02 = 0.f, a03 = 0.f;   // col 0
  float a10 = 0.f, a11 = 0.f, a12 = 0.f, a13 = 0.f;   // col 1

  if (og != 0) {
    // generic: covers og 1..13 (og==13's g=56,57 staged as zero)
#pragma unroll 4
    for (int jj = 0; jj < 16; ++jj) {
      int j = j0 + jj;
      float4 c = creg[jj];
      float x0 = xs[0][j][0], x1 = xs[0][j][1], x2 = xs[0][j][2], x3 = xs[0][j][3];
      float x4 = xs[0][j][4], x5 = xs[0][j][5], x6 = xs[0][j][6];
      a00 += c.x * x0 + c.y * x1 + c.z * x2 + c.w * x3;
      a01 += c.x * x1 + c.y * x2 + c.z * x3 + c.w * x4;
      a02 += c.x * x2 + c.y * x3 + c.z * x4 + c.w * x5;
      a03 += c.x * x3 + c.y * x4 + c.z * x5 + c.w * x6;
      float y0 = xs[1][j][0], y1 = xs[1][j][1], y2 = xs[1][j][2], y3 = xs[1][j][3];
      float y4 = xs[1][j][4], y5 = xs[1][j][5], y6 = xs[1][j][6];
      a10 += c.x * y0 + c.y * y1 + c.z * y2 + c.w * y3;
      a11 += c.x * y1 + c.y * y2 + c.z * y3 + c.w * y4;
      a12 += c.x * y2 + c.y * y3 + c.z * y4 + c.w * y5;
      a13 += c.x * y3 + c.y * y4 + c.z * y5 + c.w * y6;
    }
  } else {
    // og==0: xs[.][j][0]=row54, [1]=row55 (wrapped), [2..6]=rows 0..4
#pragma unroll 4
    for (int jj = 0; jj < 16; ++jj) {
      int j = j0 + jj;
      float4 c = creg[jj];
      float4 d = cb[4096 + j * 64];    // in-loop: keeps VGPR count low
      float x0 = xs[0][j][0], x1 = xs[0][j][1], x2 = xs[0][j][2], x3 = xs[0][j][3];
      float x4 = xs[0][j][4], x5 = xs[0][j][5], x6 = xs[0][j][6];
      a00 += d.x * x2 + d.y * x3 + d.z * x0 + d.w * x1;  // o=0: D taps
      a01 += c.y * x2 + c.z * x3 + c.w * x4;             // o=1: g=-1 tap dropped
      a02 += c.x * x2 + c.y * x3 + c.z * x4 + c.w * x5;
      a03 += c.x * x3 + c.y * x4 + c.z * x5 + c.w * x6;
      float y0 = xs[1][j][0], y1 = xs[1][j][1], y2 = xs[1][j][2], y3 = xs[1][j][3];
      float y4 = xs[1][j][4], y5 = xs[1][j][5], y6 = xs[1][j][6];
      a10 += d.x * y2 + d.y * y3 + d.z * y0 + d.w * y1;
      a11 += c.y * y2 + c.z * y3 + c.w * y4;
      a12 += c.x * y2 + c.y * y3 + c.z * y4 + c.w * y5;
      a13 += c.x * y3 + c.y * y4 + c.z * y5 + c.w * y6;
    }
  }

  red[w][0][0][i] = a00; red[w][0][1][i] = a01;
  red[w][0][2][i] = a02; red[w][0][3][i] = a03;
  red[w][1][0][i] = a10; red[w][1][1][i] = a11;
  red[w][1][2][i] = a12; red[w][1][3][i] = a13;
  __syncthreads();

  // ---- cross-wave reduction + store: thread t -> (s = t>>6, i = t&63), 2 cols
  {
    int s  = t >> 6;
    int ii = t & 63;
    float v0 = red[0][0][s][ii] + red[1][0][s][ii] + red[2][0][s][ii] + red[3][0][s][ii];
    float v1 = red[0][1][s][ii] + red[1][1][s][ii] + red[2][1][s][ii] + red[3][1][s][ii];
    float* ob = out + ii * XSTRIDE + (o0 + s) * SP + n0;
    ob[0] = v0;
    ob[1] = v1;
  }
}

extern "C" void kernel_launch(void* const* d_in, const int* in_sizes, int n_in,
                              void* d_out, int out_size, void* d_ws, size_t ws_size,
                              hipStream_t stream) {
  const float* x = (const float*)d_in[0];
  const float* W = (const float*)d_in[1];
  float* out = (float*)d_out;
  float4* Cv = (float4*)d_ws;   // 8192 float4 = 128 KB scratch

  tsc_prep<<<dim3(16), dim3(256), 0, stream>>>(W, Cv);
  tsc_main<<<dim3(14, 28), dim3(256), 0, stream>>>(x, Cv, out);
}

// Round 4
// 63.004 us; speedup vs baseline: 1.1800x; 1.1800x over previous
//
#include <hip/hip_runtime.h>

#define SP 56
#define CH 64
#define XSTRIDE 3136   // 56*56 = per-j stride in x, per-i stride in out

// ---------------------------------------------------------------------------
// Prep: build combined coefficient tables from W (64,3,2,64) = W[i][kt][l][j].
// For o>=1 the reference collapses to a 4-tap vertical correlation:
//   g=o-2: C0=W[i,0,1,j]; g=o-1: C1=W[i,0,0,j]+W[i,1,1,j];
//   g=o  : C2=W[i,1,0,j]+W[i,2,1,j]; g=o+1: C3=W[i,2,0,j]
// o==0 wraps (o-1 -> 55): taps rows {0,1,54,55} with
//   D = {W[i,1,0,j], W[i,2,0,j], W[i,0,1,j], W[i,1,1,j]}
// Layout: Cv[j*64+i] = float4(C0..C3); D table at float4 offset 4096.
// ---------------------------------------------------------------------------
__global__ void tsc_prep(const float* __restrict__ W, float4* __restrict__ Cv) {
  int t = blockIdx.x * blockDim.x + threadIdx.x;
  if (t >= CH * CH) return;
  int i = t & 63;
  int j = t >> 6;
  const float* Wi = W + i * 384 + j;   // W[i][kt][l][j]: kt stride 128, l stride 64
  float w00 = Wi[0];
  float w01 = Wi[64];
  float w10 = Wi[128];
  float w11 = Wi[192];
  float w20 = Wi[256];
  float w21 = Wi[320];
  Cv[j * 64 + i]        = make_float4(w01, w00 + w11, w10 + w21, w20);
  Cv[4096 + j * 64 + i] = make_float4(w10, w20, w01, w11);
}

// ---------------------------------------------------------------------------
// Main: block = (op 0..27, n 0..55) -> 2 output rows o = 2*op, 2*op+1, one
// column n. 1568 blocks (~6/CU) for TLP; 256 threads = 4 waves; wave w owns
// j in [16w,16w+16), lane = output channel i. R3 lesson: latency-bound ->
// maximize block count, no register coefficient arrays.
// ---------------------------------------------------------------------------
__global__ __launch_bounds__(256) void tsc_main(const float* __restrict__ x,
                                                const float4* __restrict__ Cv,
                                                float* __restrict__ out) {
  __shared__ float xs[CH][8];       // 2 KB: xs[j][b], row g = o0-2+b (wrap/zero)
  __shared__ float red[4][2][64];   // 2 KB: red[wave][s][i]

  const int t  = threadIdx.x;
  const int i  = t & 63;            // output channel (lane)
  const int w  = t >> 6;            // wave id 0..3
  const int op = blockIdx.x;        // 0..27 (o-pair)
  const int n  = blockIdx.y;        // 0..55
  const int o0 = op * 2;
  const int ns = (n + SP - 1) % SP; // (n-1) mod 56

  // ---- stage x window into LDS (2 loads per thread, coalesced in b) ----
  const float* xrow = x + ns * SP;
#pragma unroll
  for (int k = 0; k < 2; ++k) {
    int u = t + k * 256;                      // 0..511
    int j = u >> 3;
    int b = u & 7;
    int g = o0 - 2 + b;
    if (g < 0) g += SP;                       // circular bottom (only op==0)
    float v = (g < SP) ? xrow[j * XSTRIDE + g] : 0.f;  // zero-pad top
    xs[j][b] = v;
  }
  __syncthreads();

  // ---- per-wave partial sums over 16 j values, 2 output rows ----
  float a0 = 0.f, a1 = 0.f;
  const float4* cb = Cv + i;
  const int j0 = w * 16;

  if (op != 0) {
    // generic: covers op 1..27 (top-edge g>=56 staged as zero)
#pragma unroll 4
    for (int jj = 0; jj < 16; ++jj) {
      int j = j0 + jj;
      float4 c = cb[j * 64];
      float x0 = xs[j][0], x1 = xs[j][1], x2 = xs[j][2];
      float x3 = xs[j][3], x4 = xs[j][4];
      a0 += c.x * x0 + c.y * x1 + c.z * x2 + c.w * x3;
      a1 += c.x * x1 + c.y * x2 + c.z * x3 + c.w * x4;
    }
  } else {
    // op==0: xs[j][0]=row54, xs[j][1]=row55 (wrapped), xs[j][2..7]=rows 0..5
#pragma unroll 4
    for (int jj = 0; jj < 16; ++jj) {
      int j = j0 + jj;
      float4 c = cb[j * 64];
      float4 d = cb[4096 + j * 64];
      float x0 = xs[j][0], x1 = xs[j][1], x2 = xs[j][2];
      float x3 = xs[j][3], x4 = xs[j][4];
      a0 += d.x * x2 + d.y * x3 + d.z * x0 + d.w * x1;  // o=0: D taps
      a1 += c.y * x2 + c.z * x3 + c.w * x4;             // o=1: g=-1 tap dropped
    }
  }

  red[w][0][i] = a0;
  red[w][1][i] = a1;
  __syncthreads();

  // ---- cross-wave reduction + store: threads 0..127 -> (s = t>>6, i = t&63)
  if (t < 128) {
    int s  = t >> 6;
    int ii = t & 63;
    float v = red[0][s][ii] + red[1][s][ii] + red[2][s][ii] + red[3][s][ii];
    out[ii * XSTRIDE + (o0 + s) * SP + n] = v;
  }
}

extern "C" void kernel_launch(void* const* d_in, const int* in_sizes, int n_in,
                              void* d_out, int out_size, void* d_ws, size_t ws_size,
                              hipStream_t stream) {
  const float* x = (const float*)d_in[0];
  const float* W = (const float*)d_in[1];
  float* out = (float*)d_out;
  float4* Cv = (float4*)d_ws;   // 8192 float4 = 128 KB scratch

  tsc_prep<<<dim3(16), dim3(256), 0, stream>>>(W, Cv);
  tsc_main<<<dim3(28, 56), dim3(256), 0, stream>>>(x, Cv, out);
}

// Round 5
// 62.610 us; speedup vs baseline: 1.1874x; 1.0063x over previous
//
#include <hip/hip_runtime.h>

#define SP 56
#define CH 64
#define XSTRIDE 3136   // 56*56 = per-j stride in x, per-i stride in out

// ---------------------------------------------------------------------------
// Prep: build combined coefficient tables from W (64,3,2,64) = W[i][kt][l][j].
// For o>=1 the reference collapses to a 4-tap vertical correlation:
//   g=o-2: C0=W[i,0,1,j]; g=o-1: C1=W[i,0,0,j]+W[i,1,1,j];
//   g=o  : C2=W[i,1,0,j]+W[i,2,1,j]; g=o+1: C3=W[i,2,0,j]
// o==0 wraps (o-1 -> 55): taps rows {0,1,54,55} with
//   D = {W[i,1,0,j], W[i,2,0,j], W[i,0,1,j], W[i,1,1,j]}
// Layout: Cv[j*64+i] = float4(C0..C3); D table at float4 offset 4096.
//
// R5: lane mapping swapped to (j = u&63, i = u>>6) so all six W loads are
// coalesced 256B wave-transactions (j is contiguous in W's last axis).
// Stores become 1KB-strided but are fire-and-forget (no dependent use).
// ---------------------------------------------------------------------------
__global__ void tsc_prep(const float* __restrict__ W, float4* __restrict__ Cv) {
  int u = blockIdx.x * blockDim.x + threadIdx.x;
  if (u >= CH * CH) return;
  int j = u & 63;                      // lane-contiguous -> coalesced loads
  int i = u >> 6;
  const float* Wi = W + i * 384 + j;   // W[i][kt][l][j]: kt stride 128, l stride 64
  float w00 = Wi[0];
  float w01 = Wi[64];
  float w10 = Wi[128];
  float w11 = Wi[192];
  float w20 = Wi[256];
  float w21 = Wi[320];
  Cv[j * 64 + i]        = make_float4(w01, w00 + w11, w10 + w21, w20);
  Cv[4096 + j * 64 + i] = make_float4(w10, w20, w01, w11);
}

// ---------------------------------------------------------------------------
// Main: block = (op 0..27, n 0..55) -> 2 output rows o = 2*op, 2*op+1, one
// column n. 1568 blocks (~6/CU) for TLP; 256 threads = 4 waves; wave w owns
// j in [16w,16w+16), lane = output channel i. R3 lesson: latency-bound ->
// maximize block count, no register coefficient arrays. (Unchanged from R4.)
// ---------------------------------------------------------------------------
__global__ __launch_bounds__(256) void tsc_main(const float* __restrict__ x,
                                                const float4* __restrict__ Cv,
                                                float* __restrict__ out) {
  __shared__ float xs[CH][8];       // 2 KB: xs[j][b], row g = o0-2+b (wrap/zero)
  __shared__ float red[4][2][64];   // 2 KB: red[wave][s][i]

  const int t  = threadIdx.x;
  const int i  = t & 63;            // output channel (lane)
  const int w  = t >> 6;            // wave id 0..3
  const int op = blockIdx.x;        // 0..27 (o-pair)
  const int n  = blockIdx.y;        // 0..55
  const int o0 = op * 2;
  const int ns = (n + SP - 1) % SP; // (n-1) mod 56

  // ---- stage x window into LDS (2 loads per thread, coalesced in b) ----
  const float* xrow = x + ns * SP;
#pragma unroll
  for (int k = 0; k < 2; ++k) {
    int u = t + k * 256;                      // 0..511
    int j = u >> 3;
    int b = u & 7;
    int g = o0 - 2 + b;
    if (g < 0) g += SP;                       // circular bottom (only op==0)
    float v = (g < SP) ? xrow[j * XSTRIDE + g] : 0.f;  // zero-pad top
    xs[j][b] = v;
  }
  __syncthreads();

  // ---- per-wave partial sums over 16 j values, 2 output rows ----
  float a0 = 0.f, a1 = 0.f;
  const float4* cb = Cv + i;
  const int j0 = w * 16;

  if (op != 0) {
    // generic: covers op 1..27 (top-edge g>=56 staged as zero)
#pragma unroll 4
    for (int jj = 0; jj < 16; ++jj) {
      int j = j0 + jj;
      float4 c = cb[j * 64];
      float x0 = xs[j][0], x1 = xs[j][1], x2 = xs[j][2];
      float x3 = xs[j][3], x4 = xs[j][4];
      a0 += c.x * x0 + c.y * x1 + c.z * x2 + c.w * x3;
      a1 += c.x * x1 + c.y * x2 + c.z * x3 + c.w * x4;
    }
  } else {
    // op==0: xs[j][0]=row54, xs[j][1]=row55 (wrapped), xs[j][2..7]=rows 0..5
#pragma unroll 4
    for (int jj = 0; jj < 16; ++jj) {
      int j = j0 + jj;
      float4 c = cb[j * 64];
      float4 d = cb[4096 + j * 64];
      float x0 = xs[j][0], x1 = xs[j][1], x2 = xs[j][2];
      float x3 = xs[j][3], x4 = xs[j][4];
      a0 += d.x * x2 + d.y * x3 + d.z * x0 + d.w * x1;  // o=0: D taps
      a1 += c.y * x2 + c.z * x3 + c.w * x4;             // o=1: g=-1 tap dropped
    }
  }

  red[w][0][i] = a0;
  red[w][1][i] = a1;
  __syncthreads();

  // ---- cross-wave reduction + store: threads 0..127 -> (s = t>>6, i = t&63)
  if (t < 128) {
    int s  = t >> 6;
    int ii = t & 63;
    float v = red[0][s][ii] + red[1][s][ii] + red[2][s][ii] + red[3][s][ii];
    out[ii * XSTRIDE + (o0 + s) * SP + n] = v;
  }
}

extern "C" void kernel_launch(void* const* d_in, const int* in_sizes, int n_in,
                              void* d_out, int out_size, void* d_ws, size_t ws_size,
                              hipStream_t stream) {
  const float* x = (const float*)d_in[0];
  const float* W = (const float*)d_in[1];
  float* out = (float*)d_out;
  float4* Cv = (float4*)d_ws;   // 8192 float4 = 128 KB scratch

  tsc_prep<<<dim3(16), dim3(256), 0, stream>>>(W, Cv);
  tsc_main<<<dim3(28, 56), dim3(256), 0, stream>>>(x, Cv, out);
}